// Round 11
// baseline (279.710 us; speedup 1.0000x reference)
//
#include <hip/hip_runtime.h>
#include <hip/hip_bf16.h>

using bf16 = __bf16;
using bf16x8 = __attribute__((ext_vector_type(8))) __bf16;
using bf16x4 = __attribute__((ext_vector_type(4))) __bf16;
using f32x4  = __attribute__((ext_vector_type(4))) float;
using f32x16 = __attribute__((ext_vector_type(16))) float;

typedef const void __attribute__((address_space(1)))* gas_p;
typedef void __attribute__((address_space(3)))* las_p;

#define GLD16(g, l) __builtin_amdgcn_global_load_lds((gas_p)(const void*)(g), (las_p)(void*)(l), 16, 0, 0)

__device__ __forceinline__ bf16x8 lds_ld8(const void* p) {
  union { uint4 u; bf16x8 v; } c;
  c.u = *(const uint4*)p;
  return c.v;
}
__device__ __forceinline__ bf16x8 g_ld8(const bf16* p) {
  union { uint4 u; bf16x8 v; } c;
  c.u = *(const uint4*)p;
  return c.v;
}
// single-instruction 2^x
__device__ __forceinline__ float fexp2(float x) {
  float r; asm("v_exp_f32 %0, %1" : "=v"(r) : "v"(x)); return r;
}
// v_cvt_pk_bf16_f32: dst[15:0]=bf16(lo), dst[31:16]=bf16(hi)
__device__ __forceinline__ unsigned cvtpk(float lo, float hi) {
  unsigned r; asm("v_cvt_pk_bf16_f32 %0, %1, %2" : "=v"(r) : "v"(lo), "v"(hi)); return r;
}

// ---------------- f32 -> bf16 elementwise convert ----------------
__global__ void k_convert(const float* __restrict__ in, bf16* __restrict__ out, int n4) {
  int i = blockIdx.x * blockDim.x + threadIdx.x;
  if (i >= n4) return;
  float4 f = ((const float4*)in)[i];
  bf16x4 o;
  o[0] = (bf16)f.x; o[1] = (bf16)f.y; o[2] = (bf16)f.z; o[3] = (bf16)f.w;
  ((bf16x4*)out)[i] = o;
}

// ---------------- transpose + convert weights: W[K=2048][N] -> Wt[N][2048] bf16 ----------------
__global__ void k_transp(const float* __restrict__ W, bf16* __restrict__ Wt, int N, int rowOff) {
  __shared__ float tile[64][65];
  const int n0 = blockIdx.x * 64, k0 = blockIdx.y * 64;
  const int t = threadIdx.x;
#pragma unroll
  for (int i = 0; i < 16; ++i) {
    int idx = t + i * 256; int r = idx >> 6, c = idx & 63;
    tile[r][c] = W[(size_t)(k0 + r) * N + n0 + c];
  }
  __syncthreads();
#pragma unroll
  for (int i = 0; i < 16; ++i) {
    int idx = t + i * 256; int r = idx >> 6, c = idx & 63;
    Wt[(size_t)(rowOff + n0 + r) * 2048 + k0 + c] = (bf16)tile[c][r];
  }
}

// ---------------- GEMM main loop: C[128x128] += A[128xK] * Bt[128xK]^T, K=2048, BK=32 ----------------
__device__ __forceinline__ void gemm_main(const bf16* __restrict__ A, const bf16* __restrict__ Bt,
                                          int brow, int bcol, int tid, f32x4 (&acc)[4][4],
                                          char* ldsA, char* ldsB) {
  const int lane = tid & 63;
  const int l15 = lane & 15, l4 = lane >> 4;
  const int wid = tid >> 6, wr = wid >> 1, wc = wid & 1;
  const int srow = tid >> 2;
  const int sseg = (tid & 3) ^ (srow & 3);   // pre-swizzled global source (m173 pattern)
  const bf16* ga = A  + (size_t)(brow + srow) * 2048 + sseg * 8;
  const bf16* gb = Bt + (size_t)(bcol + srow) * 2048 + sseg * 8;
  char* la = ldsA + tid * 16;
  char* lb = ldsB + tid * 16;
  const int roff = (l15 & 3) << 4;

  for (int k0 = 0; k0 < 2048; k0 += 32) {
    __syncthreads();
    GLD16(ga + k0, la);
    GLD16(ga + k0 + (size_t)64 * 2048, la + 4096);
    GLD16(gb + k0, lb);
    GLD16(gb + k0 + (size_t)64 * 2048, lb + 4096);
    __syncthreads();
    bf16x8 af[4], bfr[4];
#pragma unroll
    for (int m = 0; m < 4; ++m)
      af[m] = lds_ld8(ldsA + (wr * 64 + m * 16 + l15) * 64 + ((l4 << 4) ^ roff));
#pragma unroll
    for (int n = 0; n < 4; ++n)
      bfr[n] = lds_ld8(ldsB + (wc * 64 + n * 16 + l15) * 64 + ((l4 << 4) ^ roff));
#pragma unroll
    for (int m = 0; m < 4; ++m)
#pragma unroll
      for (int n = 0; n < 4; ++n)
        acc[m][n] = __builtin_amdgcn_mfma_f32_16x16x32_bf16(af[m], bfr[n], acc[m][n], 0, 0, 0);
  }
}

// ---------------- QKV GEMM + RoPE epilogue (V written transposed + pi-permuted) ----------------
// Q scale folds 1/sqrt(64) * log2(e) so attention softmax can use exp2 directly.
// V is written as Vt[b][hk][d][pi(s)] where pi swaps bits 2<->3 of s, so the
// attention PV A-fragment (sigma k-slot order) is 16 contiguous bytes.
__global__ __launch_bounds__(256) void k_gemm_qkv(const bf16* __restrict__ A, const bf16* __restrict__ Bt,
    const float* __restrict__ cosT, const float* __restrict__ sinT,
    bf16* __restrict__ Qb, bf16* __restrict__ Kb, bf16* __restrict__ Vt) {
  __shared__ __align__(16) char ldsA[8192];
  __shared__ __align__(16) char ldsB[8192];
  const int tid = threadIdx.x;
  const int brow = blockIdx.x * 128, bcol = blockIdx.y * 128;
  f32x4 zero = {0.f, 0.f, 0.f, 0.f};
  f32x4 acc[4][4];
#pragma unroll
  for (int m = 0; m < 4; ++m)
#pragma unroll
    for (int n = 0; n < 4; ++n) acc[m][n] = zero;

  gemm_main(A, Bt, brow, bcol, tid, acc, ldsA, ldsB);

  const int lane = tid & 63, l15 = lane & 15, l4 = lane >> 4;
  const int wid = tid >> 6, wr = wid >> 1, wc = wid & 1;
  const int base64 = bcol + wc * 64;       // wave-uniform; one head per wave block
  const int rbase  = brow + wr * 64;

  if (base64 < 2048) {                      // Q segment (RoPE + 0.125*log2e scale)
    const int h = base64 >> 6;
#pragma unroll
    for (int m = 0; m < 4; ++m)
#pragma unroll
      for (int r = 0; r < 4; ++r) {
        const int row = rbase + m * 16 + l4 * 4 + r;
        const int b = row >> 11, s = row & 2047;
        float o[4];
#pragma unroll
        for (int n = 0; n < 4; ++n) {
          const int d = n * 16 + l15;
          const float cv = cosT[s * 64 + d], sv = sinT[s * 64 + d];
          const float t = acc[m][n][r], p = acc[m][n ^ 2][r];
          o[n] = (t * cv + ((n < 2) ? -p : p) * sv) * 0.18033688f;
        }
        bf16* dst = Qb + ((size_t)((b * 32 + h) * 2048 + s)) * 64;
#pragma unroll
        for (int n = 0; n < 4; ++n) dst[n * 16 + l15] = (bf16)o[n];
      }
  } else if (base64 < 2560) {               // K segment (RoPE)
    const int h = (base64 - 2048) >> 6;
#pragma unroll
    for (int m = 0; m < 4; ++m)
#pragma unroll
      for (int r = 0; r < 4; ++r) {
        const int row = rbase + m * 16 + l4 * 4 + r;
        const int b = row >> 11, s = row & 2047;
        float o[4];
#pragma unroll
        for (int n = 0; n < 4; ++n) {
          const int d = n * 16 + l15;
          const float cv = cosT[s * 64 + d], sv = sinT[s * 64 + d];
          const float t = acc[m][n][r], p = acc[m][n ^ 2][r];
          o[n] = t * cv + ((n < 2) ? -p : p) * sv;
        }
        bf16* dst = Kb + ((size_t)((b * 8 + h) * 2048 + s)) * 64;
#pragma unroll
        for (int n = 0; n < 4; ++n) dst[n * 16 + l15] = (bf16)o[n];
      }
  } else {                                  // V segment -> Vt[b][hk][d][pi(s)]
    const int h = (base64 - 2560) >> 6;
#pragma unroll
    for (int m = 0; m < 4; ++m)
#pragma unroll
      for (int r = 0; r < 4; ++r) {
        const int row = rbase + m * 16 + l4 * 4 + r;
        const int b = row >> 11, s = row & 2047;
        const int ps = (s & ~12) | ((s & 4) << 1) | ((s & 8) >> 1);  // swap bits 2,3
#pragma unroll
        for (int n = 0; n < 4; ++n) {
          const int d = n * 16 + l15;
          Vt[((size_t)((b * 8 + h) * 64 + d)) * 2048 + ps] = (bf16)acc[m][n][r];
        }
      }
  }
}

// ---------------- Flash attention (causal, GQA), 32x32 sigma body + LDS staging ----------------
// R10 structure + 64 q-rows per wave (two 32-row halves qh): each staged kv
// tile feeds 2x the MFMA work -> ds_read:MFMA 1:2, barriers and staging per
// unit work halved. q-block = 256 rows (4 waves); complement block pairing.
__global__ __launch_bounds__(256) void k_attn(const bf16* __restrict__ Qb, const bf16* __restrict__ Kb,
                                              const bf16* __restrict__ Vtp, bf16* __restrict__ ctx) {
  __shared__ __align__(16) char kvb[2][16384];  // [buf][128 rows x 128B]; rows 0-63 K, 64-127 V^T(pi)
  const int tid = threadIdx.x, lane = tid & 63, w = tid >> 6;
  const int l31 = lane & 31, hi = lane >> 5;
  // XCD-aware: XCD = p&7 owns 8 contiguous bh; complement pairing over 2 rounds
  const int p = (int)blockIdx.x;
  const int y = (p & 7) * 8 + ((p >> 3) & 7);   // bh
  const int g = p >> 6;                          // 0..7
  const int c = (g < 4) ? (7 - g) : (g - 4);     // heavy first, complement second
  const int b = y >> 5, h = y & 31, hk = h >> 2;
  const int q0w = c * 256 + w * 64;              // this wave's 64 q rows
  const int nfw = q0w >> 6;                      // wave's diagonal kv tile (= 4c+w)
  const int nt = 4 * c + 4;                      // kv tiles staged by the block

  // staging: thread t covers row srow(+32 per round), 16B segment sseg
  const int srow = tid >> 3, sseg = tid & 7;
  const bf16* kS = Kb  + ((size_t)((b * 8 + hk) * 2048)) * 64;
  const bf16* vS = Vtp + ((size_t)((b * 8 + hk) * 64)) * 2048;

  bf16x8 bq[2][4];
#pragma unroll
  for (int qh = 0; qh < 2; ++qh) {
    const bf16* qbase = Qb + ((size_t)((b * 32 + h) * 2048 + q0w + qh * 32 + l31)) * 64 + hi * 8;
#pragma unroll
    for (int dc = 0; dc < 4; ++dc) bq[qh][dc] = g_ld8(qbase + dc * 16);
  }

  const f32x16 z16 = {0,0,0,0,0,0,0,0,0,0,0,0,0,0,0,0};
  f32x16 o[2][2] = {{z16, z16}, {z16, z16}};
  float m[2] = {-3.0e38f, -3.0e38f}, ls[2] = {0.f, 0.f};
  const int sz = (l31 & 7) << 4;       // fragment-read swizzle (row&7 == l31&7)
  const int wsz = (srow & 7) << 4;     // staging-write swizzle

  uint4 st[4];
  auto stage_load = [&](int kv0) {
#pragma unroll
    for (int r4 = 0; r4 < 4; ++r4) {
      const int row = srow + (r4 & 1) * 32;
      const bf16* gp = (r4 < 2) ? (kS + (size_t)(kv0 + row) * 64 + sseg * 8)
                                : (vS + (size_t)row * 2048 + kv0 + sseg * 8);
      st[r4] = *(const uint4*)gp;
    }
  };
  auto stage_write = [&](char* buf) {
#pragma unroll
    for (int r4 = 0; r4 < 4; ++r4)
      *(uint4*)(buf + (srow + r4 * 32) * 128 + ((sseg * 16) ^ wsz)) = st[r4];
  };

  union PF { unsigned u[4]; bf16x8 v; };

  stage_load(0);
  stage_write(kvb[0]);
  __syncthreads();

  for (int kt = 0; kt < nt; ++kt) {
    char* cur = kvb[kt & 1];
    if (kt + 1 < nt) stage_load((kt + 1) * 64);   // issue early, land under compute
    if (kt <= nfw) {
      const int kv0 = kt * 64;
      // ---- K fragments from LDS (shared by both q-halves) ----
      bf16x8 ak[2][4];
#pragma unroll
      for (int kvh = 0; kvh < 2; ++kvh) {
        const int row = kvh * 32 + l31;
#pragma unroll
        for (int dc = 0; dc < 4; ++dc)
          ak[kvh][dc] = lds_ld8(cur + row * 128 + ((dc * 32 + hi * 16) ^ sz));
      }
      PF pf[2][4];
#pragma unroll
      for (int qh = 0; qh < 2; ++qh) {
        // ---- QK: sc = mfma(K, Q) ----
        f32x16 sc[2];
        __builtin_amdgcn_s_setprio(1);
#pragma unroll
        for (int kvh = 0; kvh < 2; ++kvh) {
          sc[kvh] = __builtin_amdgcn_mfma_f32_32x32x16_bf16(ak[kvh][0], bq[qh][0], z16, 0, 0, 0);
#pragma unroll
          for (int dc = 1; dc < 4; ++dc)
            sc[kvh] = __builtin_amdgcn_mfma_f32_32x32x16_bf16(ak[kvh][dc], bq[qh][dc], sc[kvh], 0, 0, 0);
        }
        __builtin_amdgcn_s_setprio(0);
        if (kt == nfw) {   // diagonal tile: mask kv > q
          const int q = q0w + qh * 32 + l31;
#pragma unroll
          for (int kvh = 0; kvh < 2; ++kvh)
#pragma unroll
            for (int r = 0; r < 16; ++r) {
              const int kv = kv0 + kvh * 32 + (r & 3) + 8 * (r >> 2) + 4 * hi;
              if (kv > q) sc[kvh][r] = -3.0e30f;
            }
        }
        // ---- softmax: tree max + one cross shuffle ----
        float t[16];
#pragma unroll
        for (int i = 0; i < 16; ++i) t[i] = fmaxf(sc[0][i], sc[1][i]);
#pragma unroll
        for (int stp = 8; stp >= 1; stp >>= 1)
#pragma unroll
          for (int i = 0; i < stp; ++i) t[i] = fmaxf(t[i], t[i + stp]);
        float mx = fmaxf(t[0], __shfl_xor(t[0], 32));
        // defer-max (T13): rescale only if max grew by > 11.5 (log2 units)
        if (!__all(mx <= m[qh] + 11.5f)) {
          const float mn = fmaxf(m[qh], mx);
          const float corr = fexp2(m[qh] - mn);
          m[qh] = mn;
          ls[qh] *= corr;
#pragma unroll
          for (int r = 0; r < 16; ++r) { o[qh][0][r] *= corr; o[qh][1][r] *= corr; }
        }
#pragma unroll
        for (int kvh = 0; kvh < 2; ++kvh)
#pragma unroll
          for (int r = 0; r < 16; ++r) sc[kvh][r] = fexp2(sc[kvh][r] - m[qh]);
        // lane-local sum tree
        float u[16];
#pragma unroll
        for (int i = 0; i < 16; ++i) u[i] = sc[0][i] + sc[1][i];
#pragma unroll
        for (int stp = 8; stp >= 1; stp >>= 1)
#pragma unroll
          for (int i = 0; i < stp; ++i) u[i] += u[i + stp];
        ls[qh] += u[0];
        // pack P into sigma-order B-fragments (lane-local registers)
#pragma unroll
        for (int kvh = 0; kvh < 2; ++kvh)
#pragma unroll
          for (int s = 0; s < 2; ++s)
#pragma unroll
            for (int tt = 0; tt < 4; ++tt)
              pf[qh][kvh * 2 + s].u[tt] = cvtpk(sc[kvh][s * 8 + 2 * tt], sc[kvh][s * 8 + 2 * tt + 1]);
      }
      // ---- PV: V fragments from LDS, shared by both q-halves ----
      __builtin_amdgcn_s_setprio(1);
#pragma unroll
      for (int cc = 0; cc < 4; ++cc)
#pragma unroll
        for (int dh = 0; dh < 2; ++dh) {
          const int row = 64 + dh * 32 + l31;
          bf16x8 av = lds_ld8(cur + row * 128 + ((cc * 32 + hi * 16) ^ sz));
          o[0][dh] = __builtin_amdgcn_mfma_f32_32x32x16_bf16(av, pf[0][cc].v, o[0][dh], 0, 0, 0);
          o[1][dh] = __builtin_amdgcn_mfma_f32_32x32x16_bf16(av, pf[1][cc].v, o[1][dh], 0, 0, 0);
        }
      __builtin_amdgcn_s_setprio(0);
    }
    if (kt + 1 < nt) stage_write(kvb[(kt + 1) & 1]);
    __syncthreads();
  }

  // ---- epilogue: normalize, transpose via per-wave LDS slice, store ----
  char* tb = kvb[0] + w * 4096;   // free after final barrier
#pragma unroll
  for (int qh = 0; qh < 2; ++qh) {
    float ll = ls[qh] + __shfl_xor(ls[qh], 32);
    const float inv = 1.0f / ll;
#pragma unroll
    for (int dh = 0; dh < 2; ++dh)
#pragma unroll
      for (int r = 0; r < 16; r += 2) {
        const unsigned wdv = cvtpk(o[qh][dh][r] * inv, o[qh][dh][r + 1] * inv);
        const int d = dh * 32 + (r & 3) + 8 * (r >> 2) + 4 * hi;
        *(unsigned*)(tb + l31 * 128 + ((d * 2) ^ sz)) = wdv;
      }
#pragma unroll
    for (int j = 0; j < 4; ++j) {
      const int off = hi * 16 + j * 32;
      uint4 val = *(const uint4*)(tb + l31 * 128 + (off ^ sz));
      *(uint4*)(ctx + ((size_t)(b * 2048 + q0w + qh * 32 + l31)) * 2048 + h * 64 + off / 2) = val;
    }
  }
}

// ---------------- Output GEMM: ctx @ Wo -> f32 ----------------
__global__ __launch_bounds__(256) void k_gemm_out(const bf16* __restrict__ A, const bf16* __restrict__ Bt,
                                                  float* __restrict__ out) {
  __shared__ __align__(16) char ldsA[8192];
  __shared__ __align__(16) char ldsB[8192];
  const int tid = threadIdx.x;
  const int brow = blockIdx.x * 128, bcol = blockIdx.y * 128;
  f32x4 zero = {0.f, 0.f, 0.f, 0.f};
  f32x4 acc[4][4];
#pragma unroll
  for (int m = 0; m < 4; ++m)
#pragma unroll
    for (int n = 0; n < 4; ++n) acc[m][n] = zero;

  gemm_main(A, Bt, brow, bcol, tid, acc, ldsA, ldsB);

  const int lane = tid & 63, l15 = lane & 15, l4 = lane >> 4;
  const int wid = tid >> 6, wr = wid >> 1, wc = wid & 1;
#pragma unroll
  for (int m = 0; m < 4; ++m)
#pragma unroll
    for (int r = 0; r < 4; ++r) {
      const int row = brow + wr * 64 + m * 16 + l4 * 4 + r;
      float* dst = out + (size_t)row * 2048 + bcol + wc * 64;
#pragma unroll
      for (int n = 0; n < 4; ++n) dst[n * 16 + l15] = acc[m][n][r];
    }
}

extern "C" void kernel_launch(void* const* d_in, const int* in_sizes, int n_in,
                              void* d_out, int out_size, void* d_ws, size_t ws_size,
                              hipStream_t stream) {
  (void)in_sizes; (void)n_in; (void)out_size;
  if (ws_size < (size_t)79691776) return;   // need ~76 MB scratch
  const float* x    = (const float*)d_in[0];
  // d_in[1] = mask (causal, hardcoded)
  const float* cosT = (const float*)d_in[2];
  const float* sinT = (const float*)d_in[3];
  const float* Wq   = (const float*)d_in[4];
  const float* Wk   = (const float*)d_in[5];
  const float* Wv   = (const float*)d_in[6];
  const float* Wo   = (const float*)d_in[7];
  char* ws = (char*)d_ws;
  bf16* xb   = (bf16*)(ws + 0);            // [4096][2048]
  bf16* wqkv = (bf16*)(ws + 16777216);     // [3072][2048]  (Wq^T | Wk^T | Wv^T)
  bf16* wo_t = (bf16*)(ws + 29360128);     // [2048][2048]
  bf16* Qb   = (bf16*)(ws + 37748736);     // [2][32][2048][64]
  bf16* Kb   = (bf16*)(ws + 54525952);     // [2][8][2048][64]
  bf16* Vt   = (bf16*)(ws + 58720256);     // [2][8][64][2048]  (transposed V, pi-permuted)
  bf16* ctxb = (bf16*)(ws + 62914560);     // [4096][2048]
  float* out = (float*)d_out;

  k_convert<<<8192, 256, 0, stream>>>(x, xb, 2097152);
  k_transp<<<dim3(32, 32), 256, 0, stream>>>(Wq, wqkv, 2048, 0);
  k_transp<<<dim3(8, 32),  256, 0, stream>>>(Wk, wqkv, 512, 2048);
  k_transp<<<dim3(8, 32),  256, 0, stream>>>(Wv, wqkv, 512, 2560);
  k_transp<<<dim3(32, 32), 256, 0, stream>>>(Wo, wo_t, 2048, 0);
  k_gemm_qkv<<<dim3(32, 24), 256, 0, stream>>>(xb, wqkv, cosT, sinT, Qb, Kb, Vt);
  k_attn<<<512, 256, 0, stream>>>(Qb, Kb, Vt, ctxb);
  k_gemm_out<<<dim3(32, 16), 256, 0, stream>>>(ctxb, wo_t, out);
}

// Round 12
// 233.923 us; speedup vs baseline: 1.1957x; 1.1957x over previous
//
#include <hip/hip_runtime.h>
#include <hip/hip_bf16.h>

using bf16 = __bf16;
using bf16x8 = __attribute__((ext_vector_type(8))) __bf16;
using bf16x4 = __attribute__((ext_vector_type(4))) __bf16;
using f32x4  = __attribute__((ext_vector_type(4))) float;
using f32x16 = __attribute__((ext_vector_type(16))) float;

typedef const void __attribute__((address_space(1)))* gas_p;
typedef void __attribute__((address_space(3)))* las_p;

#define GLD16(g, l) __builtin_amdgcn_global_load_lds((gas_p)(const void*)(g), (las_p)(void*)(l), 16, 0, 0)

__device__ __forceinline__ bf16x8 lds_ld8(const void* p) {
  union { uint4 u; bf16x8 v; } c;
  c.u = *(const uint4*)p;
  return c.v;
}
__device__ __forceinline__ bf16x8 g_ld8(const bf16* p) {
  union { uint4 u; bf16x8 v; } c;
  c.u = *(const uint4*)p;
  return c.v;
}
// single-instruction 2^x
__device__ __forceinline__ float fexp2(float x) {
  float r; asm("v_exp_f32 %0, %1" : "=v"(r) : "v"(x)); return r;
}
// v_cvt_pk_bf16_f32: dst[15:0]=bf16(lo), dst[31:16]=bf16(hi)
__device__ __forceinline__ unsigned cvtpk(float lo, float hi) {
  unsigned r; asm("v_cvt_pk_bf16_f32 %0, %1, %2" : "=v"(r) : "v"(lo), "v"(hi)); return r;
}

// ---------------- f32 -> bf16 elementwise convert ----------------
__global__ void k_convert(const float* __restrict__ in, bf16* __restrict__ out, int n4) {
  int i = blockIdx.x * blockDim.x + threadIdx.x;
  if (i >= n4) return;
  float4 f = ((const float4*)in)[i];
  bf16x4 o;
  o[0] = (bf16)f.x; o[1] = (bf16)f.y; o[2] = (bf16)f.z; o[3] = (bf16)f.w;
  ((bf16x4*)out)[i] = o;
}

// ---------------- fused transpose+convert of all four weight matrices ----------------
// W[K=2048][N] -> Wt[N][2048] bf16.  One launch covers Wq|Wk|Wv (into wqkv) and Wo (into wo_t).
__global__ void k_transp_all(const float* __restrict__ Wq, const float* __restrict__ Wk,
                             const float* __restrict__ Wv, const float* __restrict__ Wo,
                             bf16* __restrict__ wqkv, bf16* __restrict__ wo_t) {
  __shared__ float tile[64][65];
  const int id = blockIdx.x;
  const float* W; bf16* dst; int N, rowOff, bx, by;
  if (id < 1024)      { W = Wq; dst = wqkv; N = 2048; rowOff = 0;    bx = id & 31;          by = id >> 5; }
  else if (id < 1280) { int u = id - 1024; W = Wk; dst = wqkv; N = 512; rowOff = 2048; bx = u & 7; by = u >> 3; }
  else if (id < 1536) { int u = id - 1280; W = Wv; dst = wqkv; N = 512; rowOff = 2560; bx = u & 7; by = u >> 3; }
  else                { int u = id - 1536; W = Wo; dst = wo_t; N = 2048; rowOff = 0;   bx = u & 31; by = u >> 5; }
  const int n0 = bx * 64, k0 = by * 64;
  const int t = threadIdx.x;
#pragma unroll
  for (int i = 0; i < 16; ++i) {
    int idx = t + i * 256; int r = idx >> 6, c = idx & 63;
    tile[r][c] = W[(size_t)(k0 + r) * N + n0 + c];
  }
  __syncthreads();
#pragma unroll
  for (int i = 0; i < 16; ++i) {
    int idx = t + i * 256; int r = idx >> 6, c = idx & 63;
    dst[(size_t)(rowOff + n0 + r) * 2048 + k0 + c] = (bf16)tile[c][r];
  }
}

// ---------------- GEMM main loop: C[128x128] += A[128xK] * Bt[128xK]^T, K=2048, BK=64 ----------------
// BK=64 halves barrier count vs BK=32 (m97 ~20% barrier-drain stall amortized 2x).
// LDS 2x16KB; rows are 128B, XOR-swizzled by ((row&7)<<4) via pre-swizzled global source.
__device__ __forceinline__ void gemm_main(const bf16* __restrict__ A, const bf16* __restrict__ Bt,
                                          int brow, int bcol, int tid, f32x4 (&acc)[4][4],
                                          char* ldsA, char* ldsB) {
  const int lane = tid & 63;
  const int l15 = lane & 15, l4 = lane >> 4;
  const int wid = tid >> 6, wr = wid >> 1, wc = wid & 1;
  const int srow = tid >> 3;                 // 0..31
  const int xseg = (tid & 7) ^ (srow & 7);   // pre-swizzled global 16B segment (m173)
  const bf16* ga = A  + (size_t)(brow + srow) * 2048 + xseg * 8;
  const bf16* gb = Bt + (size_t)(bcol + srow) * 2048 + xseg * 8;
  char* la = ldsA + tid * 16;
  char* lb = ldsB + tid * 16;

  for (int k0 = 0; k0 < 2048; k0 += 64) {
    __syncthreads();
#pragma unroll
    for (int i = 0; i < 4; ++i) {
      GLD16(ga + k0 + (size_t)(32 * i) * 2048, la + i * 4096);
      GLD16(gb + k0 + (size_t)(32 * i) * 2048, lb + i * 4096);
    }
    __syncthreads();
#pragma unroll
    for (int kk = 0; kk < 2; ++kk) {
      bf16x8 af[4], bfr[4];
#pragma unroll
      for (int m = 0; m < 4; ++m) {
        const int row = wr * 64 + m * 16 + l15;
        af[m] = lds_ld8(ldsA + row * 128 + ((kk * 64 + l4 * 16) ^ ((row & 7) << 4)));
      }
#pragma unroll
      for (int n = 0; n < 4; ++n) {
        const int row = wc * 64 + n * 16 + l15;
        bfr[n] = lds_ld8(ldsB + row * 128 + ((kk * 64 + l4 * 16) ^ ((row & 7) << 4)));
      }
#pragma unroll
      for (int m = 0; m < 4; ++m)
#pragma unroll
        for (int n = 0; n < 4; ++n)
          acc[m][n] = __builtin_amdgcn_mfma_f32_16x16x32_bf16(af[m], bfr[n], acc[m][n], 0, 0, 0);
    }
  }
}

// ---------------- QKV GEMM + RoPE epilogue (V written transposed + pi-permuted) ----------------
// Q scale folds 1/sqrt(64) * log2(e) so attention softmax can use exp2 directly.
// V is written as Vt[b][hk][d][pi(s)] where pi swaps bits 2<->3 of s, so the
// attention PV A-fragment (sigma k-slot order) is 16 contiguous bytes.
// 1D grid, XCD-aware decode: XCD r owns bcol panels {3r,3r+1,3r+2} (1.5MB, L2-fit);
// consecutive blocks share the A row-panel.
__global__ __launch_bounds__(256) void k_gemm_qkv(const bf16* __restrict__ A, const bf16* __restrict__ Bt,
    const float* __restrict__ cosT, const float* __restrict__ sinT,
    bf16* __restrict__ Qb, bf16* __restrict__ Kb, bf16* __restrict__ Vt) {
  __shared__ __align__(16) char ldsA[16384];
  __shared__ __align__(16) char ldsB[16384];
  const int tid = threadIdx.x;
  const int p = (int)blockIdx.x, r8 = p & 7, q8 = p >> 3;   // q8 in 0..95
  const int by = r8 * 3 + q8 % 3, bx = q8 / 3;
  const int brow = bx * 128, bcol = by * 128;
  f32x4 zero = {0.f, 0.f, 0.f, 0.f};
  f32x4 acc[4][4];
#pragma unroll
  for (int m = 0; m < 4; ++m)
#pragma unroll
    for (int n = 0; n < 4; ++n) acc[m][n] = zero;

  gemm_main(A, Bt, brow, bcol, tid, acc, ldsA, ldsB);

  const int lane = tid & 63, l15 = lane & 15, l4 = lane >> 4;
  const int wid = tid >> 6, wr = wid >> 1, wc = wid & 1;
  const int base64 = bcol + wc * 64;       // wave-uniform; one head per wave block
  const int rbase  = brow + wr * 64;

  if (base64 < 2048) {                      // Q segment (RoPE + 0.125*log2e scale)
    const int h = base64 >> 6;
#pragma unroll
    for (int m = 0; m < 4; ++m)
#pragma unroll
      for (int r = 0; r < 4; ++r) {
        const int row = rbase + m * 16 + l4 * 4 + r;
        const int b = row >> 11, s = row & 2047;
        float o[4];
#pragma unroll
        for (int n = 0; n < 4; ++n) {
          const int d = n * 16 + l15;
          const float cv = cosT[s * 64 + d], sv = sinT[s * 64 + d];
          const float t = acc[m][n][r], pp = acc[m][n ^ 2][r];
          o[n] = (t * cv + ((n < 2) ? -pp : pp) * sv) * 0.18033688f;
        }
        bf16* dst = Qb + ((size_t)((b * 32 + h) * 2048 + s)) * 64;
#pragma unroll
        for (int n = 0; n < 4; ++n) dst[n * 16 + l15] = (bf16)o[n];
      }
  } else if (base64 < 2560) {               // K segment (RoPE)
    const int h = (base64 - 2048) >> 6;
#pragma unroll
    for (int m = 0; m < 4; ++m)
#pragma unroll
      for (int r = 0; r < 4; ++r) {
        const int row = rbase + m * 16 + l4 * 4 + r;
        const int b = row >> 11, s = row & 2047;
        float o[4];
#pragma unroll
        for (int n = 0; n < 4; ++n) {
          const int d = n * 16 + l15;
          const float cv = cosT[s * 64 + d], sv = sinT[s * 64 + d];
          const float t = acc[m][n][r], pp = acc[m][n ^ 2][r];
          o[n] = t * cv + ((n < 2) ? -pp : pp) * sv;
        }
        bf16* dst = Kb + ((size_t)((b * 8 + h) * 2048 + s)) * 64;
#pragma unroll
        for (int n = 0; n < 4; ++n) dst[n * 16 + l15] = (bf16)o[n];
      }
  } else {                                  // V segment -> Vt[b][hk][d][pi(s)]
    const int h = (base64 - 2560) >> 6;
#pragma unroll
    for (int m = 0; m < 4; ++m)
#pragma unroll
      for (int r = 0; r < 4; ++r) {
        const int row = rbase + m * 16 + l4 * 4 + r;
        const int b = row >> 11, s = row & 2047;
        const int ps = (s & ~12) | ((s & 4) << 1) | ((s & 8) >> 1);  // swap bits 2,3
#pragma unroll
        for (int n = 0; n < 4; ++n) {
          const int d = n * 16 + l15;
          Vt[((size_t)((b * 8 + h) * 64 + d)) * 2048 + ps] = (bf16)acc[m][n][r];
        }
      }
  }
}

// ---------------- Flash attention (causal, GQA), 32x32 sigma body + LDS staging ----------------
// R10 structure (verified 118us): 4-wave blocks share each 64-kv tile via
// double-buffered LDS (coalesced global reads, XOR-swizzled rows); 32x32
// swapped-operand sigma body; fragments from ds_read_b128.
// R12: per-CU balanced chunk permutation (each CU's 4 resident blocks sum to 30).
__global__ __launch_bounds__(256) void k_attn(const bf16* __restrict__ Qb, const bf16* __restrict__ Kb,
                                              const bf16* __restrict__ Vtp, bf16* __restrict__ ctx) {
  __shared__ __align__(16) char kvb[2][16384];  // [buf][128 rows x 128B]; rows 0-63 K, 64-127 V^T(pi)
  const int tid = threadIdx.x, lane = tid & 63, w = tid >> 6;
  const int l31 = lane & 31, hi = lane >> 5;
  // XCD-aware: XCD = p&7 owns 8 contiguous bh; chunk via balanced permutation
  const int p = (int)blockIdx.x;
  const int y = (p & 7) * 8 + ((p >> 3) & 7);   // bh
  const int j = p >> 6;                          // 0..15
  const int c = (int)((0xD95126AEC84037BFULL >> (4 * j)) & 15);  // groups {j,j+4,j+8,j+12} sum 30
  const int b = y >> 5, h = y & 31, hk = h >> 2;
  const int q0 = c * 128 + w * 32;               // this wave's 32 q rows
  const int nf = (q0 + 31) >> 6;                 // wave's diagonal kv tile
  const int nt = 2 * c + 2;                      // kv tiles staged by the block

  // staging: thread t covers row srow(+32 per round), 16B segment sseg
  const int srow = tid >> 3, sseg = tid & 7;
  const bf16* kS = Kb  + ((size_t)((b * 8 + hk) * 2048)) * 64;
  const bf16* vS = Vtp + ((size_t)((b * 8 + hk) * 64)) * 2048;

  const bf16* qbase = Qb + ((size_t)((b * 32 + h) * 2048 + q0 + l31)) * 64 + hi * 8;
  bf16x8 bq[4];
#pragma unroll
  for (int dc = 0; dc < 4; ++dc) bq[dc] = g_ld8(qbase + dc * 16);

  const f32x16 z16 = {0,0,0,0,0,0,0,0,0,0,0,0,0,0,0,0};
  f32x16 o[2] = {z16, z16};
  float m = -3.0e38f, lsum = 0.f;
  const int sz = (l31 & 7) << 4;       // fragment-read swizzle (row&7 == l31&7)
  const int wsz = (srow & 7) << 4;     // staging-write swizzle

  uint4 st[4];
  auto stage_load = [&](int kv0) {
#pragma unroll
    for (int r4 = 0; r4 < 4; ++r4) {
      const int row = srow + (r4 & 1) * 32;
      const bf16* g = (r4 < 2) ? (kS + (size_t)(kv0 + row) * 64 + sseg * 8)
                               : (vS + (size_t)row * 2048 + kv0 + sseg * 8);
      st[r4] = *(const uint4*)g;
    }
  };
  auto stage_write = [&](char* buf) {
#pragma unroll
    for (int r4 = 0; r4 < 4; ++r4)
      *(uint4*)(buf + (srow + r4 * 32) * 128 + ((sseg * 16) ^ wsz)) = st[r4];
  };

  stage_load(0);
  stage_write(kvb[0]);
  __syncthreads();

  for (int kt = 0; kt < nt; ++kt) {
    char* cur = kvb[kt & 1];
    if (kt + 1 < nt) stage_load((kt + 1) * 64);   // issue early, land under compute
    if (kt <= nf) {
      const int kv0 = kt * 64;
      // ---- QK: sc = mfma(K, Q), K fragments from LDS ----
      f32x16 sc[2];
      __builtin_amdgcn_s_setprio(1);
#pragma unroll
      for (int kvh = 0; kvh < 2; ++kvh) {
        const int row = kvh * 32 + l31;
        bf16x8 a0 = lds_ld8(cur + row * 128 + ((hi * 16) ^ sz));
        sc[kvh] = __builtin_amdgcn_mfma_f32_32x32x16_bf16(a0, bq[0], z16, 0, 0, 0);
#pragma unroll
        for (int dc = 1; dc < 4; ++dc) {
          bf16x8 ad = lds_ld8(cur + row * 128 + ((dc * 32 + hi * 16) ^ sz));
          sc[kvh] = __builtin_amdgcn_mfma_f32_32x32x16_bf16(ad, bq[dc], sc[kvh], 0, 0, 0);
        }
      }
      __builtin_amdgcn_s_setprio(0);
      if (kt == nf) {   // diagonal tile: mask kv > q
        const int q = q0 + l31;
#pragma unroll
        for (int kvh = 0; kvh < 2; ++kvh)
#pragma unroll
          for (int r = 0; r < 16; ++r) {
            const int kv = kv0 + kvh * 32 + (r & 3) + 8 * (r >> 2) + 4 * hi;
            if (kv > q) sc[kvh][r] = -3.0e30f;
          }
      }
      // ---- softmax: tree max + one cross shuffle ----
      float t[16];
#pragma unroll
      for (int i = 0; i < 16; ++i) t[i] = fmaxf(sc[0][i], sc[1][i]);
#pragma unroll
      for (int stp = 8; stp >= 1; stp >>= 1)
#pragma unroll
        for (int i = 0; i < stp; ++i) t[i] = fmaxf(t[i], t[i + stp]);
      float mx = fmaxf(t[0], __shfl_xor(t[0], 32));
      // defer-max (T13): rescale only if max grew by > 11.5 (log2 units)
      if (!__all(mx <= m + 11.5f)) {
        const float mn = fmaxf(m, mx);
        const float corr = fexp2(m - mn);
        m = mn;
        lsum *= corr;
#pragma unroll
        for (int r = 0; r < 16; ++r) { o[0][r] *= corr; o[1][r] *= corr; }
      }
#pragma unroll
      for (int kvh = 0; kvh < 2; ++kvh)
#pragma unroll
        for (int r = 0; r < 16; ++r) sc[kvh][r] = fexp2(sc[kvh][r] - m);
      // ---- PV: P B-fragment = own sc registers (sigma); V(pi) from LDS ----
#pragma unroll
      for (int kvh = 0; kvh < 2; ++kvh)
#pragma unroll
        for (int s = 0; s < 2; ++s) {
          union { unsigned u[4]; bf16x8 v; } f;
#pragma unroll
          for (int tt = 0; tt < 4; ++tt)
            f.u[tt] = cvtpk(sc[kvh][s * 8 + 2 * tt], sc[kvh][s * 8 + 2 * tt + 1]);
          const int cc = kvh * 2 + s;
          __builtin_amdgcn_s_setprio(1);
#pragma unroll
          for (int dh = 0; dh < 2; ++dh) {
            const int row = 64 + dh * 32 + l31;
            bf16x8 av = lds_ld8(cur + row * 128 + ((cc * 32 + hi * 16) ^ sz));
            o[dh] = __builtin_amdgcn_mfma_f32_32x32x16_bf16(av, f.v, o[dh], 0, 0, 0);
          }
          __builtin_amdgcn_s_setprio(0);
        }
      // ---- lane-local sum tree ----
      float u[16];
#pragma unroll
      for (int i = 0; i < 16; ++i) u[i] = sc[0][i] + sc[1][i];
#pragma unroll
      for (int stp = 8; stp >= 1; stp >>= 1)
#pragma unroll
        for (int i = 0; i < stp; ++i) u[i] += u[i + stp];
      lsum += u[0];
    }
    if (kt + 1 < nt) stage_write(kvb[(kt + 1) & 1]);
    __syncthreads();
  }

  // ---- epilogue: normalize, transpose via per-wave LDS slice, store ----
  float ll = lsum + __shfl_xor(lsum, 32);
  const float inv = 1.0f / ll;
  char* tb = kvb[0] + w * 4096;   // free after final barrier
#pragma unroll
  for (int dh = 0; dh < 2; ++dh)
#pragma unroll
    for (int r = 0; r < 16; r += 2) {
      const unsigned wdv = cvtpk(o[dh][r] * inv, o[dh][r + 1] * inv);
      const int d = dh * 32 + (r & 3) + 8 * (r >> 2) + 4 * hi;
      *(unsigned*)(tb + l31 * 128 + ((d * 2) ^ sz)) = wdv;
    }
#pragma unroll
  for (int jj = 0; jj < 4; ++jj) {
    const int off = hi * 16 + jj * 32;
    uint4 val = *(const uint4*)(tb + l31 * 128 + (off ^ sz));
    *(uint4*)(ctx + ((size_t)(b * 2048 + q0 + l31)) * 2048 + h * 64 + off / 2) = val;
  }
}

// ---------------- Output GEMM: ctx @ Wo -> f32 ----------------
// 1D grid, XCD-aware decode: XCD r owns bcol panels {2r, 2r+1}.
__global__ __launch_bounds__(256) void k_gemm_out(const bf16* __restrict__ A, const bf16* __restrict__ Bt,
                                                  float* __restrict__ out) {
  __shared__ __align__(16) char ldsA[16384];
  __shared__ __align__(16) char ldsB[16384];
  const int tid = threadIdx.x;
  const int p = (int)blockIdx.x, r8 = p & 7, q8 = p >> 3;   // q8 in 0..63
  const int by = r8 * 2 + (q8 & 1), bx = q8 >> 1;
  const int brow = bx * 128, bcol = by * 128;
  f32x4 zero = {0.f, 0.f, 0.f, 0.f};
  f32x4 acc[4][4];
#pragma unroll
  for (int m = 0; m < 4; ++m)
#pragma unroll
    for (int n = 0; n < 4; ++n) acc[m][n] = zero;

  gemm_main(A, Bt, brow, bcol, tid, acc, ldsA, ldsB);

  const int lane = tid & 63, l15 = lane & 15, l4 = lane >> 4;
  const int wid = tid >> 6, wr = wid >> 1, wc = wid & 1;
#pragma unroll
  for (int m = 0; m < 4; ++m)
#pragma unroll
    for (int r = 0; r < 4; ++r) {
      const int row = brow + wr * 64 + m * 16 + l4 * 4 + r;
      float* dst = out + (size_t)row * 2048 + bcol + wc * 64;
#pragma unroll
      for (int n = 0; n < 4; ++n) dst[n * 16 + l15] = acc[m][n][r];
    }
}

extern "C" void kernel_launch(void* const* d_in, const int* in_sizes, int n_in,
                              void* d_out, int out_size, void* d_ws, size_t ws_size,
                              hipStream_t stream) {
  (void)in_sizes; (void)n_in; (void)out_size;
  if (ws_size < (size_t)79691776) return;   // need ~76 MB scratch
  const float* x    = (const float*)d_in[0];
  // d_in[1] = mask (causal, hardcoded)
  const float* cosT = (const float*)d_in[2];
  const float* sinT = (const float*)d_in[3];
  const float* Wq   = (const float*)d_in[4];
  const float* Wk   = (const float*)d_in[5];
  const float* Wv   = (const float*)d_in[6];
  const float* Wo   = (const float*)d_in[7];
  char* ws = (char*)d_ws;
  bf16* xb   = (bf16*)(ws + 0);            // [4096][2048]
  bf16* wqkv = (bf16*)(ws + 16777216);     // [3072][2048]  (Wq^T | Wk^T | Wv^T)
  bf16* wo_t = (bf16*)(ws + 29360128);     // [2048][2048]
  bf16* Qb   = (bf16*)(ws + 37748736);     // [2][32][2048][64]
  bf16* Kb   = (bf16*)(ws + 54525952);     // [2][8][2048][64]
  bf16* Vt   = (bf16*)(ws + 58720256);     // [2][8][64][2048]  (transposed V, pi-permuted)
  bf16* ctxb = (bf16*)(ws + 62914560);     // [4096][2048]
  float* out = (float*)d_out;

  k_convert<<<8192, 256, 0, stream>>>(x, xb, 2097152);
  k_transp_all<<<2560, 256, 0, stream>>>(Wq, Wk, Wv, Wo, wqkv, wo_t);
  k_gemm_qkv<<<768, 256, 0, stream>>>(xb, wqkv, cosT, sinT, Qb, Kb, Vt);
  k_attn<<<1024, 256, 0, stream>>>(Qb, Kb, Vt, ctxb);
  k_gemm_out<<<512, 256, 0, stream>>>(ctxb, wo_t, out);
}

// Round 13
// 211.352 us; speedup vs baseline: 1.3234x; 1.1068x over previous
//
#include <hip/hip_runtime.h>
#include <hip/hip_bf16.h>

using bf16 = __bf16;
using bf16x8 = __attribute__((ext_vector_type(8))) __bf16;
using bf16x4 = __attribute__((ext_vector_type(4))) __bf16;
using f32x4  = __attribute__((ext_vector_type(4))) float;
using f32x16 = __attribute__((ext_vector_type(16))) float;

typedef const void __attribute__((address_space(1)))* gas_p;
typedef void __attribute__((address_space(3)))* las_p;

#define GLD16(g, l) __builtin_amdgcn_global_load_lds((gas_p)(const void*)(g), (las_p)(void*)(l), 16, 0, 0)

__device__ __forceinline__ bf16x8 lds_ld8(const void* p) {
  union { uint4 u; bf16x8 v; } c;
  c.u = *(const uint4*)p;
  return c.v;
}
__device__ __forceinline__ bf16x8 g_ld8(const bf16* p) {
  union { uint4 u; bf16x8 v; } c;
  c.u = *(const uint4*)p;
  return c.v;
}
// single-instruction 2^x
__device__ __forceinline__ float fexp2(float x) {
  float r; asm("v_exp_f32 %0, %1" : "=v"(r) : "v"(x)); return r;
}
// v_cvt_pk_bf16_f32: dst[15:0]=bf16(lo), dst[31:16]=bf16(hi)
__device__ __forceinline__ unsigned cvtpk(float lo, float hi) {
  unsigned r; asm("v_cvt_pk_bf16_f32 %0, %1, %2" : "=v"(r) : "v"(lo), "v"(hi)); return r;
}

// ---------------- f32 -> bf16 elementwise convert ----------------
__global__ void k_convert(const float* __restrict__ in, bf16* __restrict__ out, int n4) {
  int i = blockIdx.x * blockDim.x + threadIdx.x;
  if (i >= n4) return;
  float4 f = ((const float4*)in)[i];
  bf16x4 o;
  o[0] = (bf16)f.x; o[1] = (bf16)f.y; o[2] = (bf16)f.z; o[3] = (bf16)f.w;
  ((bf16x4*)out)[i] = o;
}

// ---------------- fused transpose+convert of all four weight matrices ----------------
// W[K=2048][N] -> Wt[N][2048] bf16.  One launch covers Wq|Wk|Wv (into wqkv) and Wo (into wo_t).
__global__ void k_transp_all(const float* __restrict__ Wq, const float* __restrict__ Wk,
                             const float* __restrict__ Wv, const float* __restrict__ Wo,
                             bf16* __restrict__ wqkv, bf16* __restrict__ wo_t) {
  __shared__ float tile[64][65];
  const int id = blockIdx.x;
  const float* W; bf16* dst; int N, rowOff, bx, by;
  if (id < 1024)      { W = Wq; dst = wqkv; N = 2048; rowOff = 0;    bx = id & 31;          by = id >> 5; }
  else if (id < 1280) { int u = id - 1024; W = Wk; dst = wqkv; N = 512; rowOff = 2048; bx = u & 7; by = u >> 3; }
  else if (id < 1536) { int u = id - 1280; W = Wv; dst = wqkv; N = 512; rowOff = 2560; bx = u & 7; by = u >> 3; }
  else                { int u = id - 1536; W = Wo; dst = wo_t; N = 2048; rowOff = 0;   bx = u & 31; by = u >> 5; }
  const int n0 = bx * 64, k0 = by * 64;
  const int t = threadIdx.x;
#pragma unroll
  for (int i = 0; i < 16; ++i) {
    int idx = t + i * 256; int r = idx >> 6, c = idx & 63;
    tile[r][c] = W[(size_t)(k0 + r) * N + n0 + c];
  }
  __syncthreads();
#pragma unroll
  for (int i = 0; i < 16; ++i) {
    int idx = t + i * 256; int r = idx >> 6, c = idx & 63;
    dst[(size_t)(rowOff + n0 + r) * 2048 + k0 + c] = (bf16)tile[c][r];
  }
}

// ---------------- GEMM main loop: C[128x128] += A[128xK] * Bt[128xK]^T, K=2048, BK=64 ----------------
// BK=64 halves barrier count vs BK=32 (m97 ~20% barrier-drain stall amortized 2x).
// LDS 2x16KB; rows are 128B, XOR-swizzled by ((row&7)<<4) via pre-swizzled global source.
__device__ __forceinline__ void gemm_main(const bf16* __restrict__ A, const bf16* __restrict__ Bt,
                                          int brow, int bcol, int tid, f32x4 (&acc)[4][4],
                                          char* ldsA, char* ldsB) {
  const int lane = tid & 63;
  const int l15 = lane & 15, l4 = lane >> 4;
  const int wid = tid >> 6, wr = wid >> 1, wc = wid & 1;
  const int srow = tid >> 3;                 // 0..31
  const int xseg = (tid & 7) ^ (srow & 7);   // pre-swizzled global 16B segment (m173)
  const bf16* ga = A  + (size_t)(brow + srow) * 2048 + xseg * 8;
  const bf16* gb = Bt + (size_t)(bcol + srow) * 2048 + xseg * 8;
  char* la = ldsA + tid * 16;
  char* lb = ldsB + tid * 16;

  for (int k0 = 0; k0 < 2048; k0 += 64) {
    __syncthreads();
#pragma unroll
    for (int i = 0; i < 4; ++i) {
      GLD16(ga + k0 + (size_t)(32 * i) * 2048, la + i * 4096);
      GLD16(gb + k0 + (size_t)(32 * i) * 2048, lb + i * 4096);
    }
    __syncthreads();
#pragma unroll
    for (int kk = 0; kk < 2; ++kk) {
      bf16x8 af[4], bfr[4];
#pragma unroll
      for (int m = 0; m < 4; ++m) {
        const int row = wr * 64 + m * 16 + l15;
        af[m] = lds_ld8(ldsA + row * 128 + ((kk * 64 + l4 * 16) ^ ((row & 7) << 4)));
      }
#pragma unroll
      for (int n = 0; n < 4; ++n) {
        const int row = wc * 64 + n * 16 + l15;
        bfr[n] = lds_ld8(ldsB + row * 128 + ((kk * 64 + l4 * 16) ^ ((row & 7) << 4)));
      }
#pragma unroll
      for (int m = 0; m < 4; ++m)
#pragma unroll
        for (int n = 0; n < 4; ++n)
          acc[m][n] = __builtin_amdgcn_mfma_f32_16x16x32_bf16(af[m], bfr[n], acc[m][n], 0, 0, 0);
    }
  }
}

// ---------------- QKV GEMM + RoPE epilogue (V written transposed + pi-permuted) ----------------
// Q scale folds 1/sqrt(64) * log2(e) so attention softmax can use exp2 directly.
// V is written as Vt[b][hk][d][pi(s)] where pi swaps bits 2<->3 of s, so the
// attention PV A-fragment (sigma k-slot order) is 16 contiguous bytes.
// 1D grid, XCD-aware decode: XCD r owns bcol panels {3r,3r+1,3r+2} (1.5MB, L2-fit);
// consecutive blocks share the A row-panel.
__global__ __launch_bounds__(256) void k_gemm_qkv(const bf16* __restrict__ A, const bf16* __restrict__ Bt,
    const float* __restrict__ cosT, const float* __restrict__ sinT,
    bf16* __restrict__ Qb, bf16* __restrict__ Kb, bf16* __restrict__ Vt) {
  __shared__ __align__(16) char ldsA[16384];
  __shared__ __align__(16) char ldsB[16384];
  const int tid = threadIdx.x;
  const int p = (int)blockIdx.x, r8 = p & 7, q8 = p >> 3;   // q8 in 0..95
  const int by = r8 * 3 + q8 % 3, bx = q8 / 3;
  const int brow = bx * 128, bcol = by * 128;
  f32x4 zero = {0.f, 0.f, 0.f, 0.f};
  f32x4 acc[4][4];
#pragma unroll
  for (int m = 0; m < 4; ++m)
#pragma unroll
    for (int n = 0; n < 4; ++n) acc[m][n] = zero;

  gemm_main(A, Bt, brow, bcol, tid, acc, ldsA, ldsB);

  const int lane = tid & 63, l15 = lane & 15, l4 = lane >> 4;
  const int wid = tid >> 6, wr = wid >> 1, wc = wid & 1;
  const int base64 = bcol + wc * 64;       // wave-uniform; one head per wave block
  const int rbase  = brow + wr * 64;

  if (base64 < 2048) {                      // Q segment (RoPE + 0.125*log2e scale)
    const int h = base64 >> 6;
#pragma unroll
    for (int m = 0; m < 4; ++m)
#pragma unroll
      for (int r = 0; r < 4; ++r) {
        const int row = rbase + m * 16 + l4 * 4 + r;
        const int b = row >> 11, s = row & 2047;
        float o[4];
#pragma unroll
        for (int n = 0; n < 4; ++n) {
          const int d = n * 16 + l15;
          const float cv = cosT[s * 64 + d], sv = sinT[s * 64 + d];
          const float t = acc[m][n][r], pp = acc[m][n ^ 2][r];
          o[n] = (t * cv + ((n < 2) ? -pp : pp) * sv) * 0.18033688f;
        }
        bf16* dst = Qb + ((size_t)((b * 32 + h) * 2048 + s)) * 64;
#pragma unroll
        for (int n = 0; n < 4; ++n) dst[n * 16 + l15] = (bf16)o[n];
      }
  } else if (base64 < 2560) {               // K segment (RoPE)
    const int h = (base64 - 2048) >> 6;
#pragma unroll
    for (int m = 0; m < 4; ++m)
#pragma unroll
      for (int r = 0; r < 4; ++r) {
        const int row = rbase + m * 16 + l4 * 4 + r;
        const int b = row >> 11, s = row & 2047;
        float o[4];
#pragma unroll
        for (int n = 0; n < 4; ++n) {
          const int d = n * 16 + l15;
          const float cv = cosT[s * 64 + d], sv = sinT[s * 64 + d];
          const float t = acc[m][n][r], pp = acc[m][n ^ 2][r];
          o[n] = t * cv + ((n < 2) ? -pp : pp) * sv;
        }
        bf16* dst = Kb + ((size_t)((b * 8 + h) * 2048 + s)) * 64;
#pragma unroll
        for (int n = 0; n < 4; ++n) dst[n * 16 + l15] = (bf16)o[n];
      }
  } else {                                  // V segment -> Vt[b][hk][d][pi(s)]
    const int h = (base64 - 2560) >> 6;
#pragma unroll
    for (int m = 0; m < 4; ++m)
#pragma unroll
      for (int r = 0; r < 4; ++r) {
        const int row = rbase + m * 16 + l4 * 4 + r;
        const int b = row >> 11, s = row & 2047;
        const int ps = (s & ~12) | ((s & 4) << 1) | ((s & 8) >> 1);  // swap bits 2,3
#pragma unroll
        for (int n = 0; n < 4; ++n) {
          const int d = n * 16 + l15;
          Vt[((size_t)((b * 8 + h) * 64 + d)) * 2048 + ps] = (bf16)acc[m][n][r];
        }
      }
  }
}

// ---------------- Flash attention (causal, GQA), 32x32 sigma body + LDS staging ----------------
// R10/R12 verified body. R13: zero-tail chunk pairing -- every block processes
// the chunk pair (15-j, j) sequentially (34 stage-tiles, identical for ALL
// blocks -> 2 identical blocks/CU, 8 waves/CU flat, no drain). The staging
// double-buffer runs continuously across the chunk boundary; mid-kernel
// epilogue uses a separate tbuf so kvb is never disturbed.
__global__ __launch_bounds__(256) void k_attn(const bf16* __restrict__ Qb, const bf16* __restrict__ Kb,
                                              const bf16* __restrict__ Vtp, bf16* __restrict__ ctx) {
  __shared__ __align__(16) char kvb[2][16384];  // [buf][128 rows x 128B]; rows 0-63 K, 64-127 V^T(pi)
  __shared__ __align__(16) char tbuf[4][4096];  // per-wave epilogue transpose buffer
  const int tid = threadIdx.x, lane = tid & 63, w = tid >> 6;
  const int l31 = lane & 31, hi = lane >> 5;
  // XCD-aware: XCD = p&7 owns 8 contiguous bh values; j = pair index
  const int p = (int)blockIdx.x;
  const int y = (p & 7) * 8 + ((p >> 3) & 7);   // bh
  const int j = p >> 6;                          // 0..7
  const int b = y >> 5, h = y & 31, hk = h >> 2;
  const int ntA = 2 * (15 - j) + 2;              // heavy chunk first
  const int NT = 34;                             // ntA + ntB, identical for all blocks

  // staging: thread t covers row srow(+32 per round), 16B segment sseg
  const int srow = tid >> 3, sseg = tid & 7;
  const bf16* kS = Kb  + ((size_t)((b * 8 + hk) * 2048)) * 64;
  const bf16* vS = Vtp + ((size_t)((b * 8 + hk) * 64)) * 2048;
  const int sz = (l31 & 7) << 4;       // fragment-read swizzle (row&7 == l31&7)
  const int wsz = (srow & 7) << 4;     // staging-write swizzle

  const f32x16 z16 = {0,0,0,0,0,0,0,0,0,0,0,0,0,0,0,0};
  f32x16 o[2];
  float m, lsum;
  bf16x8 bq[4];
  int c = 15 - j;
  int q0 = c * 128 + w * 32;
  int nf = (q0 + 31) >> 6;

  auto load_q = [&]() {
    const bf16* qbase = Qb + ((size_t)((b * 32 + h) * 2048 + q0 + l31)) * 64 + hi * 8;
#pragma unroll
    for (int dc = 0; dc < 4; ++dc) bq[dc] = g_ld8(qbase + dc * 16);
  };
  load_q();
  o[0] = z16; o[1] = z16; m = -3.0e38f; lsum = 0.f;

  uint4 st[4];
  auto stage_load = [&](int kv0) {
#pragma unroll
    for (int r4 = 0; r4 < 4; ++r4) {
      const int row = srow + (r4 & 1) * 32;
      const bf16* g = (r4 < 2) ? (kS + (size_t)(kv0 + row) * 64 + sseg * 8)
                               : (vS + (size_t)row * 2048 + kv0 + sseg * 8);
      st[r4] = *(const uint4*)g;
    }
  };
  auto stage_write = [&](char* buf) {
#pragma unroll
    for (int r4 = 0; r4 < 4; ++r4)
      *(uint4*)(buf + (srow + r4 * 32) * 128 + ((sseg * 16) ^ wsz)) = st[r4];
  };

  auto epilogue = [&]() {
    float ll = lsum + __shfl_xor(lsum, 32);
    const float inv = 1.0f / ll;
    char* tb = tbuf[w];
#pragma unroll
    for (int dh = 0; dh < 2; ++dh)
#pragma unroll
      for (int r = 0; r < 16; r += 2) {
        const unsigned wdv = cvtpk(o[dh][r] * inv, o[dh][r + 1] * inv);
        const int d = dh * 32 + (r & 3) + 8 * (r >> 2) + 4 * hi;
        *(unsigned*)(tb + l31 * 128 + ((d * 2) ^ sz)) = wdv;
      }
#pragma unroll
    for (int jj = 0; jj < 4; ++jj) {
      const int off = hi * 16 + jj * 32;
      uint4 val = *(const uint4*)(tb + l31 * 128 + (off ^ sz));
      *(uint4*)(ctx + ((size_t)(b * 2048 + q0 + l31)) * 2048 + h * 64 + off / 2) = val;
    }
  };

  stage_load(0);
  stage_write(kvb[0]);
  __syncthreads();

  for (int g = 0; g < NT; ++g) {
    const int kt = (g < ntA) ? g : g - ntA;
    char* cur = kvb[g & 1];
    if (g + 1 < NT) {
      const int gn = g + 1;
      const int ktn = (gn < ntA) ? gn : gn - ntA;
      stage_load(ktn * 64);                      // issue early, land under compute
    }
    if (kt <= nf) {
      const int kv0 = kt * 64;
      // ---- QK: sc = mfma(K, Q), K fragments from LDS ----
      f32x16 sc[2];
      __builtin_amdgcn_s_setprio(1);
#pragma unroll
      for (int kvh = 0; kvh < 2; ++kvh) {
        const int row = kvh * 32 + l31;
        bf16x8 a0 = lds_ld8(cur + row * 128 + ((hi * 16) ^ sz));
        sc[kvh] = __builtin_amdgcn_mfma_f32_32x32x16_bf16(a0, bq[0], z16, 0, 0, 0);
#pragma unroll
        for (int dc = 1; dc < 4; ++dc) {
          bf16x8 ad = lds_ld8(cur + row * 128 + ((dc * 32 + hi * 16) ^ sz));
          sc[kvh] = __builtin_amdgcn_mfma_f32_32x32x16_bf16(ad, bq[dc], sc[kvh], 0, 0, 0);
        }
      }
      __builtin_amdgcn_s_setprio(0);
      if (kt == nf) {   // diagonal tile: mask kv > q
        const int q = q0 + l31;
#pragma unroll
        for (int kvh = 0; kvh < 2; ++kvh)
#pragma unroll
          for (int r = 0; r < 16; ++r) {
            const int kv = kv0 + kvh * 32 + (r & 3) + 8 * (r >> 2) + 4 * hi;
            if (kv > q) sc[kvh][r] = -3.0e30f;
          }
      }
      // ---- softmax: tree max + one cross shuffle ----
      float t[16];
#pragma unroll
      for (int i = 0; i < 16; ++i) t[i] = fmaxf(sc[0][i], sc[1][i]);
#pragma unroll
      for (int stp = 8; stp >= 1; stp >>= 1)
#pragma unroll
        for (int i = 0; i < stp; ++i) t[i] = fmaxf(t[i], t[i + stp]);
      float mx = fmaxf(t[0], __shfl_xor(t[0], 32));
      // defer-max (T13): rescale only if max grew by > 11.5 (log2 units)
      if (!__all(mx <= m + 11.5f)) {
        const float mn = fmaxf(m, mx);
        const float corr = fexp2(m - mn);
        m = mn;
        lsum *= corr;
#pragma unroll
        for (int r = 0; r < 16; ++r) { o[0][r] *= corr; o[1][r] *= corr; }
      }
#pragma unroll
      for (int kvh = 0; kvh < 2; ++kvh)
#pragma unroll
        for (int r = 0; r < 16; ++r) sc[kvh][r] = fexp2(sc[kvh][r] - m);
      // ---- PV: P B-fragment = own sc registers (sigma); V(pi) from LDS ----
#pragma unroll
      for (int kvh = 0; kvh < 2; ++kvh)
#pragma unroll
        for (int s = 0; s < 2; ++s) {
          union { unsigned u[4]; bf16x8 v; } f;
#pragma unroll
          for (int tt = 0; tt < 4; ++tt)
            f.u[tt] = cvtpk(sc[kvh][s * 8 + 2 * tt], sc[kvh][s * 8 + 2 * tt + 1]);
          const int cc = kvh * 2 + s;
          __builtin_amdgcn_s_setprio(1);
#pragma unroll
          for (int dh = 0; dh < 2; ++dh) {
            const int row = 64 + dh * 32 + l31;
            bf16x8 av = lds_ld8(cur + row * 128 + ((cc * 32 + hi * 16) ^ sz));
            o[dh] = __builtin_amdgcn_mfma_f32_32x32x16_bf16(av, f.v, o[dh], 0, 0, 0);
          }
          __builtin_amdgcn_s_setprio(0);
        }
      // ---- lane-local sum tree ----
      float u[16];
#pragma unroll
      for (int i = 0; i < 16; ++i) u[i] = sc[0][i] + sc[1][i];
#pragma unroll
      for (int stp = 8; stp >= 1; stp >>= 1)
#pragma unroll
        for (int i = 0; i < stp; ++i) u[i] += u[i + stp];
      lsum += u[0];
    }
    if (g + 1 < NT) stage_write(kvb[(g + 1) & 1]);
    __syncthreads();
    if (g == ntA - 1) {
      // chunk A done for all waves (nf <= ntA-1): store it, reset for chunk B
      epilogue();
      c = j; q0 = c * 128 + w * 32; nf = (q0 + 31) >> 6;
      load_q();
      o[0] = z16; o[1] = z16; m = -3.0e38f; lsum = 0.f;
    }
  }
  epilogue();
}

// ---------------- Output GEMM: ctx @ Wo -> f32 ----------------
// 1D grid, XCD-aware decode: XCD r owns bcol panels {2r, 2r+1}.
__global__ __launch_bounds__(256) void k_gemm_out(const bf16* __restrict__ A, const bf16* __restrict__ Bt,
                                                  float* __restrict__ out) {
  __shared__ __align__(16) char ldsA[16384];
  __shared__ __align__(16) char ldsB[16384];
  const int tid = threadIdx.x;
  const int p = (int)blockIdx.x, r8 = p & 7, q8 = p >> 3;   // q8 in 0..63
  const int by = r8 * 2 + (q8 & 1), bx = q8 >> 1;
  const int brow = bx * 128, bcol = by * 128;
  f32x4 zero = {0.f, 0.f, 0.f, 0.f};
  f32x4 acc[4][4];
#pragma unroll
  for (int m = 0; m < 4; ++m)
#pragma unroll
    for (int n = 0; n < 4; ++n) acc[m][n] = zero;

  gemm_main(A, Bt, brow, bcol, tid, acc, ldsA, ldsB);

  const int lane = tid & 63, l15 = lane & 15, l4 = lane >> 4;
  const int wid = tid >> 6, wr = wid >> 1, wc = wid & 1;
#pragma unroll
  for (int m = 0; m < 4; ++m)
#pragma unroll
    for (int r = 0; r < 4; ++r) {
      const int row = brow + wr * 64 + m * 16 + l4 * 4 + r;
      float* dst = out + (size_t)row * 2048 + bcol + wc * 64;
#pragma unroll
      for (int n = 0; n < 4; ++n) dst[n * 16 + l15] = acc[m][n][r];
    }
}

extern "C" void kernel_launch(void* const* d_in, const int* in_sizes, int n_in,
                              void* d_out, int out_size, void* d_ws, size_t ws_size,
                              hipStream_t stream) {
  (void)in_sizes; (void)n_in; (void)out_size;
  if (ws_size < (size_t)79691776) return;   // need ~76 MB scratch
  const float* x    = (const float*)d_in[0];
  // d_in[1] = mask (causal, hardcoded)
  const float* cosT = (const float*)d_in[2];
  const float* sinT = (const float*)d_in[3];
  const float* Wq   = (const float*)d_in[4];
  const float* Wk   = (const float*)d_in[5];
  const float* Wv   = (const float*)d_in[6];
  const float* Wo   = (const float*)d_in[7];
  char* ws = (char*)d_ws;
  bf16* xb   = (bf16*)(ws + 0);            // [4096][2048]
  bf16* wqkv = (bf16*)(ws + 16777216);     // [3072][2048]  (Wq^T | Wk^T | Wv^T)
  bf16* wo_t = (bf16*)(ws + 29360128);     // [2048][2048]
  bf16* Qb   = (bf16*)(ws + 37748736);     // [2][32][2048][64]
  bf16* Kb   = (bf16*)(ws + 54525952);     // [2][8][2048][64]
  bf16* Vt   = (bf16*)(ws + 58720256);     // [2][8][64][2048]  (transposed V, pi-permuted)
  bf16* ctxb = (bf16*)(ws + 62914560);     // [4096][2048]
  float* out = (float*)d_out;

  k_convert<<<8192, 256, 0, stream>>>(x, xb, 2097152);
  k_transp_all<<<2560, 256, 0, stream>>>(Wq, Wk, Wv, Wo, wqkv, wo_t);
  k_gemm_qkv<<<768, 256, 0, stream>>>(xb, wqkv, cosT, sinT, Qb, Kb, Vt);
  k_attn<<<512, 256, 0, stream>>>(Qb, Kb, Vt, ctxb);
  k_gemm_out<<<512, 256, 0, stream>>>(ctxb, wo_t, out);
}